// Round 1
// baseline (103.202 us; speedup 1.0000x reference)
//
#include <hip/hip_runtime.h>

typedef _Float16 half8 __attribute__((ext_vector_type(8)));
typedef float f32x4 __attribute__((ext_vector_type(4)));

#define P_DIM 1024
#define BM 64
#define BK 64

// Pack [W_w (48 rows); G_w (8 rows); zeros (8 rows)] as f16 [64][1024] row-major,
// plus combined bias [64] (W_b, G_b, zeros) into workspace.
__global__ __launch_bounds__(256) void prep_weights(
    const float* __restrict__ Gw, const float* __restrict__ Gb,
    const float* __restrict__ Ww, const float* __restrict__ Wb,
    _Float16* __restrict__ Wf, float* __restrict__ biasC) {
  int i = blockIdx.x * 256 + threadIdx.x;   // 0 .. 64*1024-1
  int r = i >> 10, c = i & 1023;
  float v = 0.0f;
  if (r < 48) v = Ww[r * P_DIM + c];
  else if (r < 56) v = Gw[(r - 48) * P_DIM + c];
  Wf[i] = (_Float16)v;
  if (i < 64) {
    float bv = 0.0f;
    if (i < 48) bv = Wb[i];
    else if (i < 56) bv = Gb[i - 48];
    biasC[i] = bv;
  }
}

__global__ __launch_bounds__(256, 4) void fused_gate(
    const float* __restrict__ x, const _Float16* __restrict__ Wf,
    const float* __restrict__ biasC, float* __restrict__ out, int nchunks) {
  // Staging LDS: f16 [64 rows][72 f16] (stride 144 B, 16B-aligned, pad kills
  // the 128B-stride bank aliasing on ds_read_b128). Double buffered.
  __shared__ __align__(16) _Float16 As[2][BM * 72];
  // Epilogue scratch: pre-activations, padded stride 65 (bank-spread).
  __shared__ float S[BM][65];

  const int tid  = threadIdx.x;
  const int lane = tid & 63;
  const int wm   = tid >> 6;        // wave id 0..3 -> m-tile
  const int r    = tid >> 2;        // staging row 0..63
  const int q    = tid & 3;         // staging k-quarter (16 floats each)
  const int row0 = blockIdx.x * BM;

  const float* xrow = x + (size_t)(row0 + r) * P_DIM + q * 16;
  const int l15 = lane & 15;
  const int lk  = (lane >> 4) * 8;  // k-offset of this lane's fragment
  const _Float16* wbase = Wf + l15 * P_DIM + lk;
  const int arow_off = (wm * 16 + l15) * 72 + lk;

  f32x4 acc[4];
#pragma unroll
  for (int t = 0; t < 4; ++t) acc[t] = (f32x4){0.f, 0.f, 0.f, 0.f};

  // prefetch chunk 0 into registers
  float4 st[4];
#pragma unroll
  for (int g = 0; g < 4; ++g) st[g] = ((const float4*)xrow)[g];

  for (int c = 0; c < nchunks; ++c) {
    const int buf = c & 1;
    // convert staged chunk c to f16, write LDS
    {
      const float* sf = (const float*)st;
      half8 h0, h1;
#pragma unroll
      for (int i = 0; i < 8; ++i) {
        h0[i] = (_Float16)sf[i];
        h1[i] = (_Float16)sf[8 + i];
      }
      _Float16* dst = &As[buf][r * 72 + q * 16];
      *(half8*)dst = h0;
      *(half8*)(dst + 8) = h1;
    }
    __syncthreads();
    // issue global loads for chunk c+1 (hide HBM latency under MFMA phase)
    if (c + 1 < nchunks) {
      const float* gp = xrow + (c + 1) * BK;
#pragma unroll
      for (int g = 0; g < 4; ++g) st[g] = ((const float4*)gp)[g];
    }
    // MFMA phase: A from LDS, B from global (L2-resident 128 KB)
    {
      half8 a0 = *(const half8*)&As[buf][arow_off];
      half8 a1 = *(const half8*)&As[buf][arow_off + 32];
      const _Float16* wp = wbase + c * BK;
#pragma unroll
      for (int t = 0; t < 4; ++t) {
        half8 b0 = *(const half8*)(wp + t * 16 * P_DIM);
        half8 b1 = *(const half8*)(wp + t * 16 * P_DIM + 32);
        acc[t] = __builtin_amdgcn_mfma_f32_16x16x32_f16(a0, b0, acc[t], 0, 0, 0);
        acc[t] = __builtin_amdgcn_mfma_f32_16x16x32_f16(a1, b1, acc[t], 0, 0, 0);
      }
    }
  }

  // acc -> LDS with bias. D layout: col = lane&15, row = (lane>>4)*4 + reg.
#pragma unroll
  for (int t = 0; t < 4; ++t) {
    float bias = biasC[16 * t + l15];
#pragma unroll
    for (int rr = 0; rr < 4; ++rr) {
      S[wm * 16 + (lane >> 4) * 4 + rr][16 * t + l15] = acc[t][rr] + bias;
    }
  }
  __syncthreads();

  // Epilogue: 4 threads per row; thread handles experts [sub*16, sub*16+16).
  const int r2  = tid >> 2;
  const int sub = tid & 3;

  float lg[8];
#pragma unroll
  for (int k = 0; k < 8; ++k) lg[k] = S[r2][48 + k];
  float mx = lg[0];
#pragma unroll
  for (int k = 1; k < 8; ++k) mx = fmaxf(mx, lg[k]);
  float w[8];
  float ssum = 0.f;
#pragma unroll
  for (int k = 0; k < 8; ++k) { w[k] = expf(lg[k] - mx); ssum += w[k]; }
  const float inv = 1.0f / ssum;

  float mix[16];
#pragma unroll
  for (int i = 0; i < 16; ++i) mix[i] = 0.f;

#pragma unroll
  for (int k = 0; k < 8; ++k) {
    float z[6];
#pragma unroll
    for (int j = 0; j < 6; ++j) {
      float tt = S[r2][k * 6 + j];
      float tc = fminf(fmaxf(tt, -0.25f), 0.25f);
      // smooth_step: -16 tc^3 + 3 tc + 0.5
      z[j] = fmaf(tc, fmaf(-16.0f * tc, tc, 3.0f), 0.5f);
    }
    // bits 4,5 of expert index fixed by sub
    float f4 = (sub & 1) ? z[4] : 1.0f - z[4];
    float f5 = (sub & 2) ? z[5] : 1.0f - z[5];
    float wf = w[k] * inv * f4 * f5;
    // product tree over bits 0..3 (index = sum b_j 2^j), all static indices
    float t2[2], t4[4], t8[8], t16[16];
    t2[0] = 1.0f - z[0]; t2[1] = z[0];
#pragma unroll
    for (int i = 0; i < 2; ++i) { t4[i] = t2[i] * (1.0f - z[1]); t4[i + 2] = t2[i] * z[1]; }
#pragma unroll
    for (int i = 0; i < 4; ++i) { t8[i] = t4[i] * (1.0f - z[2]); t8[i + 4] = t4[i] * z[2]; }
#pragma unroll
    for (int i = 0; i < 8; ++i) { t16[i] = t8[i] * (1.0f - z[3]); t16[i + 8] = t8[i] * z[3]; }
#pragma unroll
    for (int i = 0; i < 16; ++i) mix[i] = fmaf(wf, t16[i], mix[i]);
  }

  float* op = out + (size_t)(row0 + r2) * 64 + sub * 16;
#pragma unroll
  for (int g = 0; g < 4; ++g) {
    float4 o;
    o.x = mix[4 * g + 0]; o.y = mix[4 * g + 1];
    o.z = mix[4 * g + 2]; o.w = mix[4 * g + 3];
    ((float4*)op)[g] = o;
  }
}

extern "C" void kernel_launch(void* const* d_in, const int* in_sizes, int n_in,
                              void* d_out, int out_size, void* d_ws, size_t ws_size,
                              hipStream_t stream) {
  const float* x  = (const float*)d_in[0];
  const float* Gw = (const float*)d_in[1];
  const float* Gb = (const float*)d_in[2];
  const float* Ww = (const float*)d_in[3];
  const float* Wb = (const float*)d_in[4];
  float* out = (float*)d_out;

  // workspace: 64*1024 f16 weights (128 KB) + 64 f32 bias
  _Float16* Wf   = (_Float16*)d_ws;
  float*    bias = (float*)((char*)d_ws + 64 * P_DIM * sizeof(_Float16));

  const int B = in_sizes[0] / P_DIM;

  prep_weights<<<dim3(256), dim3(256), 0, stream>>>(Gw, Gb, Ww, Wb, Wf, bias);
  fused_gate<<<dim3(B / BM), dim3(256), 0, stream>>>(x, Wf, bias, out, P_DIM / BK);
  (void)n_in; (void)out_size; (void)ws_size;
}